// Round 1
// baseline (2526.954 us; speedup 1.0000x reference)
//
#include <hip/hip_runtime.h>

// ---------------- problem constants ----------------
#define F_INPUT 32
#define C16 16
#define C32 32
#define NGRAPH 64
#define NCLS 13

static inline int cdiv(int a, int b){ return (a + b - 1) / b; }

// ---------------- degree / norm ----------------
__global__ void k_deg(const int* __restrict__ col, int* __restrict__ deg, int E){
  int e = blockIdx.x * blockDim.x + threadIdx.x;
  if (e < E) atomicAdd(&deg[col[e]], 1);
}

__global__ void k_dinv(const int* __restrict__ deg, float* __restrict__ dinv, int n){
  int v = blockIdx.x * blockDim.x + threadIdx.x;
  if (v < n){ int d = deg[v]; dinv[v] = d > 0 ? rsqrtf((float)d) : 0.f; }
}

// ---------------- prefix scan (3 kernels, chunk=1024) ----------------
__global__ void k_scan1(const int* __restrict__ deg, int* __restrict__ bsum, int n){
  __shared__ int sh[256];
  int base = blockIdx.x * 1024;
  int s = 0;
  #pragma unroll
  for (int j = 0; j < 4; j++){ int i = base + j*256 + threadIdx.x; if (i < n) s += deg[i]; }
  sh[threadIdx.x] = s; __syncthreads();
  for (int off = 128; off > 0; off >>= 1){
    if (threadIdx.x < off) sh[threadIdx.x] += sh[threadIdx.x + off];
    __syncthreads();
  }
  if (threadIdx.x == 0) bsum[blockIdx.x] = sh[0];
}

__global__ void k_scan2(const int* __restrict__ bsum, int* __restrict__ boff, int nb,
                        int* __restrict__ offsets, int n){
  if (blockIdx.x == 0 && threadIdx.x == 0){
    int acc = 0;
    for (int b = 0; b < nb; b++){ boff[b] = acc; acc += bsum[b]; }
    offsets[n] = acc;
  }
}

__global__ void k_scan3(const int* __restrict__ deg, const int* __restrict__ boff,
                        int* __restrict__ offsets, int* __restrict__ cursor, int n){
  __shared__ int sh[256];
  int base = blockIdx.x * 1024 + threadIdx.x * 4;
  int v0=0, v1=0, v2=0, v3=0;
  if (base+0 < n) v0 = deg[base+0];
  if (base+1 < n) v1 = deg[base+1];
  if (base+2 < n) v2 = deg[base+2];
  if (base+3 < n) v3 = deg[base+3];
  int s = v0+v1+v2+v3;
  sh[threadIdx.x] = s; __syncthreads();
  for (int off = 1; off < 256; off <<= 1){
    int add = 0;
    if (threadIdx.x >= off) add = sh[threadIdx.x - off];
    __syncthreads();
    sh[threadIdx.x] += add;
    __syncthreads();
  }
  int excl = sh[threadIdx.x] - s + boff[blockIdx.x];
  if (base+0 < n){ offsets[base+0]=excl; cursor[base+0]=excl; excl += v0; }
  if (base+1 < n){ offsets[base+1]=excl; cursor[base+1]=excl; excl += v1; }
  if (base+2 < n){ offsets[base+2]=excl; cursor[base+2]=excl; excl += v2; }
  if (base+3 < n){ offsets[base+3]=excl; cursor[base+3]=excl; excl += v3; }
}

__global__ void k_fill(const int* __restrict__ row, const int* __restrict__ col,
                       int* __restrict__ cursor, int* __restrict__ csr, int E){
  int e = blockIdx.x * blockDim.x + threadIdx.x;
  if (e < E){
    int d = col[e];
    int slot = atomicAdd(&cursor[d], 1);
    csr[slot] = row[e];
  }
}

// ---------------- x[N,32] @ W[4,32,16] -> z0(+bias_total), z1, z2, z3p(pre-scaled) ----------------
__global__ void k_xw4(const float* __restrict__ X, const float* __restrict__ W,
                      const float* __restrict__ b, const float* __restrict__ dinv,
                      float* __restrict__ z0, float* __restrict__ z1,
                      float* __restrict__ z2, float* __restrict__ z3p, int n){
  __shared__ float sW[2048];   // 4*32*16
  __shared__ float sb[16];
  for (int i = threadIdx.x; i < 2048; i += blockDim.x) sW[i] = W[i];
  if (threadIdx.x < 16)
    sb[threadIdx.x] = b[threadIdx.x] + b[16+threadIdx.x] + b[32+threadIdx.x] + b[48+threadIdx.x];
  __syncthreads();
  int v = blockIdx.x * blockDim.x + threadIdx.x;
  if (v >= n) return;
  float xr[32];
  const float4* xp = (const float4*)(X + (size_t)v * 32);
  #pragma unroll
  for (int j = 0; j < 8; j++){ float4 t = xp[j]; xr[4*j]=t.x; xr[4*j+1]=t.y; xr[4*j+2]=t.z; xr[4*j+3]=t.w; }
  float dv = dinv[v];
  #pragma unroll
  for (int k = 0; k < 4; k++){
    float o[16];
    #pragma unroll
    for (int c = 0; c < 16; c++) o[c] = 0.f;
    const float* wk = &sW[k * 512];
    #pragma unroll
    for (int i = 0; i < 32; i++){
      float xi = xr[i];
      #pragma unroll
      for (int c = 0; c < 16; c++) o[c] += xi * wk[i*16 + c];
    }
    float* dst;
    if (k == 0){
      #pragma unroll
      for (int c = 0; c < 16; c++) o[c] += sb[c];
      dst = z0;
    } else if (k == 1) dst = z1;
    else if (k == 2) dst = z2;
    else {
      #pragma unroll
      for (int c = 0; c < 16; c++) o[c] *= dv;
      dst = z3p;
    }
    float4* dp = (float4*)(dst + (size_t)v * 16);
    #pragma unroll
    for (int j = 0; j < 4; j++) dp[j] = make_float4(o[4*j], o[4*j+1], o[4*j+2], o[4*j+3]);
  }
}

// ---------------- propagation: s = dinv[v]*sum_e p[src] (+add[v]) (relu?) ; write h=s, p=dinv*s ----------------
// 64 lanes per node: lane = esub*16 + c ; esub = 4 edges in flight, c = channel
__global__ void k_prop(const int* __restrict__ offs, const int* __restrict__ csr,
                       const float* __restrict__ dinv, const float* __restrict__ pin,
                       const float* __restrict__ addv, float* __restrict__ hout,
                       float* __restrict__ pout, int do_relu, int n){
  int v = (int)((blockIdx.x * (size_t)blockDim.x + threadIdx.x) >> 6);
  if (v >= n) return;
  int lane = threadIdx.x & 63;
  int c = lane & 15;
  int esub = lane >> 4;
  int e0 = offs[v], e1 = offs[v+1];
  float acc = 0.f;
  for (int e = e0 + esub; e < e1; e += 4){
    int src = csr[e];
    acc += pin[(size_t)src * 16 + c];
  }
  acc += __shfl_down(acc, 32);
  acc += __shfl_down(acc, 16);
  if (esub == 0){
    float dv = dinv[v];
    float s = dv * acc;
    if (addv) s += addv[(size_t)v * 16 + c];
    if (do_relu) s = fmaxf(s, 0.f);
    if (hout) hout[(size_t)v * 16 + c] = s;
    if (pout) pout[(size_t)v * 16 + c] = dv * s;
  }
}

// ---------------- layer2 combine: h2 = relu(sum_k g_k @ W2[k] + btot) ----------------
__global__ void k_lin4(const float* __restrict__ g0, const float* __restrict__ g1,
                       const float* __restrict__ g2, const float* __restrict__ g3,
                       const float* __restrict__ W, const float* __restrict__ b,
                       float* __restrict__ h2, int n){
  __shared__ float sW[2048];   // 4*16*32
  __shared__ float sb[32];
  for (int i = threadIdx.x; i < 2048; i += blockDim.x) sW[i] = W[i];
  if (threadIdx.x < 32)
    sb[threadIdx.x] = b[threadIdx.x] + b[32+threadIdx.x] + b[64+threadIdx.x] + b[96+threadIdx.x];
  __syncthreads();
  int v = blockIdx.x * blockDim.x + threadIdx.x;
  if (v >= n) return;
  float o[32];
  #pragma unroll
  for (int c = 0; c < 32; c++) o[c] = sb[c];
  #pragma unroll
  for (int k = 0; k < 4; k++){
    const float* gk = (k==0) ? g0 : (k==1) ? g1 : (k==2) ? g2 : g3;
    const float4* gp = (const float4*)(gk + (size_t)v * 16);
    float gr[16];
    #pragma unroll
    for (int j = 0; j < 4; j++){ float4 t = gp[j]; gr[4*j]=t.x; gr[4*j+1]=t.y; gr[4*j+2]=t.z; gr[4*j+3]=t.w; }
    const float* wk = &sW[k * 512];
    #pragma unroll
    for (int i = 0; i < 16; i++){
      float gi = gr[i];
      #pragma unroll
      for (int c = 0; c < 32; c++) o[c] += gi * wk[i*32 + c];
    }
  }
  float4* dp = (float4*)(h2 + (size_t)v * 32);
  #pragma unroll
  for (int j = 0; j < 8; j++)
    dp[j] = make_float4(fmaxf(o[4*j],0.f), fmaxf(o[4*j+1],0.f), fmaxf(o[4*j+2],0.f), fmaxf(o[4*j+3],0.f));
}

// ---------------- global mean pool (batch sorted, 64 graphs, C=16) ----------------
__global__ void k_pool(const float* __restrict__ h, const int* __restrict__ batch,
                       float* __restrict__ pooled, float* __restrict__ cnt, int n){
  __shared__ float sacc[NGRAPH * 16];
  __shared__ float scnt[NGRAPH];
  for (int i = threadIdx.x; i < NGRAPH*16; i += blockDim.x) sacc[i] = 0.f;
  if (threadIdx.x < NGRAPH) scnt[threadIdx.x] = 0.f;
  __syncthreads();
  int t = blockIdx.x * blockDim.x + threadIdx.x;
  int c = t & 15;
  int stride = (gridDim.x * blockDim.x) >> 4;
  for (int v = t >> 4; v < n; v += stride){
    int b = batch[v];
    atomicAdd(&sacc[b*16 + c], h[(size_t)v*16 + c]);
    if (c == 0) atomicAdd(&scnt[b], 1.f);
  }
  __syncthreads();
  for (int i = threadIdx.x; i < NGRAPH*16; i += blockDim.x)
    if (sacc[i] != 0.f) atomicAdd(&pooled[i], sacc[i]);
  if (threadIdx.x < NGRAPH && scnt[threadIdx.x] != 0.f) atomicAdd(&cnt[threadIdx.x], scnt[threadIdx.x]);
}

// ---------------- head: pooled/cnt @ Wfc + bfc, log_softmax ----------------
__global__ void k_head(const float* __restrict__ pooled, const float* __restrict__ cnt,
                       const float* __restrict__ Wfc, const float* __restrict__ bfc,
                       float* __restrict__ out){
  int g = threadIdx.x;
  if (g >= NGRAPH) return;
  float cc = fmaxf(cnt[g], 1.f);
  float p[16];
  #pragma unroll
  for (int i = 0; i < 16; i++) p[i] = pooled[g*16 + i] / cc;
  float logits[NCLS];
  #pragma unroll
  for (int j = 0; j < NCLS; j++){
    float s = bfc[j];
    #pragma unroll
    for (int i = 0; i < 16; i++) s += p[i] * Wfc[i*NCLS + j];
    logits[j] = s;
  }
  float m = logits[0];
  #pragma unroll
  for (int j = 1; j < NCLS; j++) m = fmaxf(m, logits[j]);
  float l = 0.f;
  #pragma unroll
  for (int j = 0; j < NCLS; j++) l += expf(logits[j] - m);
  l = logf(l);
  #pragma unroll
  for (int j = 0; j < NCLS; j++) out[g*NCLS + j] = logits[j] - m - l;
}

// ---------------- launcher ----------------
extern "C" void kernel_launch(void* const* d_in, const int* in_sizes, int n_in,
                              void* d_out, int out_size, void* d_ws, size_t ws_size,
                              hipStream_t stream) {
  const float* x    = (const float*)d_in[0];
  const int*   ei   = (const int*)  d_in[1];
  const int*   batch= (const int*)  d_in[2];
  const float* W1   = (const float*)d_in[3];
  const float* b1   = (const float*)d_in[4];
  const float* W2   = (const float*)d_in[5];
  const float* b2   = (const float*)d_in[6];
  const float* W3   = (const float*)d_in[7];
  const float* b3   = (const float*)d_in[8];
  const float* Wfc  = (const float*)d_in[9];
  const float* bfc  = (const float*)d_in[10];
  float* out = (float*)d_out;

  const int N = in_sizes[0] / F_INPUT;
  const int E = in_sizes[1] / 2;
  const int* row = ei;
  const int* col = ei + E;

  // bump allocator over d_ws
  char* w = (char*)d_ws;
  auto alloc = [&](size_t bytes)->char*{
    char* p = w;
    w += (bytes + 255) & ~(size_t)255;
    return p;
  };
  int*   deg     = (int*)  alloc((size_t)N * 4);
  int*   cursor  = (int*)  alloc((size_t)N * 4);
  int*   offsets = (int*)  alloc(((size_t)N + 1) * 4);
  int*   bsum    = (int*)  alloc(1024);
  int*   boff    = (int*)  alloc(1024);
  float* dinv    = (float*)alloc((size_t)N * 4);
  int*   csr     = (int*)  alloc((size_t)E * 4);
  float* B0      = (float*)alloc((size_t)N * 16 * 4);
  float* B1      = (float*)alloc((size_t)N * 16 * 4);
  float* B2      = (float*)alloc((size_t)N * 16 * 4);
  float* B3      = (float*)alloc((size_t)N * 16 * 4);
  float* B4      = (float*)alloc((size_t)N * 16 * 4);
  float* B5      = (float*)alloc((size_t)N * 16 * 4);
  float* H2      = (float*)alloc((size_t)N * 32 * 4);
  float* pooled  = (float*)alloc((size_t)(NGRAPH*16 + NGRAPH) * 4);
  float* cnt     = pooled + NGRAPH*16;
  (void)ws_size; (void)n_in; (void)out_size;

  const int NB = cdiv(N, 1024);

  // ---- CSR build ----
  hipMemsetAsync(deg, 0, (size_t)N * 4, stream);
  k_deg  <<<cdiv(E,256), 256, 0, stream>>>(col, deg, E);
  k_dinv <<<cdiv(N,256), 256, 0, stream>>>(deg, dinv, N);
  k_scan1<<<NB, 256, 0, stream>>>(deg, bsum, N);
  k_scan2<<<1, 1, 0, stream>>>(bsum, boff, NB, offsets, N);
  k_scan3<<<NB, 256, 0, stream>>>(deg, boff, offsets, cursor, N);
  k_fill <<<cdiv(E,256), 256, 0, stream>>>(row, col, cursor, csr, E);

  const int PROP_BLOCKS = cdiv(N, 4);  // 4 nodes(waves)/block

  // ---- Layer 1 (32 -> 16, Horner, propagate at C=16) ----
  k_xw4<<<cdiv(N,256), 256, 0, stream>>>(x, W1, b1, dinv, B0, B1, B2, B3, N);
  k_prop<<<PROP_BLOCKS, 256, 0, stream>>>(offsets, csr, dinv, B3, B2, nullptr, B2, 0, N); // p2
  k_prop<<<PROP_BLOCKS, 256, 0, stream>>>(offsets, csr, dinv, B2, B1, nullptr, B1, 0, N); // p1
  k_prop<<<PROP_BLOCKS, 256, 0, stream>>>(offsets, csr, dinv, B1, B0, B0, B3, 1, N);      // h1=B0, p_h1=B3

  // ---- Layer 2 (16 -> 32, standard form, propagate at C=16) ----
  k_prop<<<PROP_BLOCKS, 256, 0, stream>>>(offsets, csr, dinv, B3, nullptr, B1, B2, 0, N); // g1=B1, p_g1=B2
  k_prop<<<PROP_BLOCKS, 256, 0, stream>>>(offsets, csr, dinv, B2, nullptr, B4, B5, 0, N); // g2=B4, p_g2=B5
  k_prop<<<PROP_BLOCKS, 256, 0, stream>>>(offsets, csr, dinv, B5, nullptr, B2, nullptr, 0, N); // g3=B2
  k_lin4<<<cdiv(N,256), 256, 0, stream>>>(B0, B1, B4, B2, W2, b2, H2, N);

  // ---- Layer 3 (32 -> 16, Horner) ----
  k_xw4<<<cdiv(N,256), 256, 0, stream>>>(H2, W3, b3, dinv, B0, B1, B2, B3, N);
  k_prop<<<PROP_BLOCKS, 256, 0, stream>>>(offsets, csr, dinv, B3, B2, nullptr, B2, 0, N);
  k_prop<<<PROP_BLOCKS, 256, 0, stream>>>(offsets, csr, dinv, B2, B1, nullptr, B1, 0, N);
  k_prop<<<PROP_BLOCKS, 256, 0, stream>>>(offsets, csr, dinv, B1, B0, B4, nullptr, 1, N); // h3=B4

  // ---- pool + head ----
  hipMemsetAsync(pooled, 0, (size_t)(NGRAPH*16 + NGRAPH) * 4, stream);
  k_pool<<<512, 256, 0, stream>>>(B4, batch, pooled, cnt, N);
  k_head<<<1, 64, 0, stream>>>(pooled, cnt, Wfc, bfc, out);
}

// Round 2
// 1799.729 us; speedup vs baseline: 1.4041x; 1.4041x over previous
//
#include <hip/hip_runtime.h>

// ---------------- problem constants ----------------
#define F_INPUT 32
#define NGRAPH 64
#define NCLS 13

// CSR bucket-build parameters
#define DPB 391          // dsts per bucket (local_dst fits 9 bits)
#define NBUCK_MAX 512
#define CAP 14336        // per-bucket edge capacity (mean 12500, +16 sigma)
#define PART_CHUNK 8192  // edges per partition block

static inline int cdiv(int a, int b){ return (a + b - 1) / b; }

// ---------------- phase A: partition edges into dst-range buckets ----------------
// packed[b*CAP + j] = (src << 9) | (dst - b*DPB)
__global__ __launch_bounds__(1024)
void k_part(const int* __restrict__ row, const int* __restrict__ col,
            int* __restrict__ gcur, int* __restrict__ packed, int E, int nbuck){
  __shared__ int scol[PART_CHUNK];
  __shared__ int hist[NBUCK_MAX];
  __shared__ int gbase[NBUCK_MAX];
  __shared__ int cur[NBUCK_MAX];
  int t = threadIdx.x;
  for (int i = t; i < NBUCK_MAX; i += 1024) hist[i] = 0;
  __syncthreads();
  int base = blockIdx.x * PART_CHUNK;
  int nloc = min(PART_CHUNK, E - base);
  for (int i = t; i < nloc; i += 1024){
    int c = col[base + i];
    scol[i] = c;
    atomicAdd(&hist[c / DPB], 1);
  }
  __syncthreads();
  if (t < nbuck){
    gbase[t] = atomicAdd(&gcur[t], hist[t]);   // one global atomic per bucket per block
    cur[t] = 0;
  }
  __syncthreads();
  for (int i = t; i < nloc; i += 1024){
    int c = scol[i];
    int b = c / DPB;
    int j = gbase[b] + atomicAdd(&cur[b], 1);
    if (j < CAP){
      int src = row[base + i];
      packed[(size_t)b * CAP + j] = (src << 9) | (c - b * DPB);
    }
  }
}

// ---------------- phase B: per-bucket CSR fill + offsets + dinv ----------------
__global__ __launch_bounds__(1024)
void k_bfill(const int* __restrict__ gcur, const int* __restrict__ packed,
             int* __restrict__ csr, int* __restrict__ offA, int* __restrict__ offB,
             float* __restrict__ dinv, int N){
  __shared__ int hist[1024];
  __shared__ int scan[1024];
  __shared__ int cur[512];
  int b = blockIdx.x;
  int t = threadIdx.x;
  int d0 = b * DPB;
  int nd = min(DPB, N - d0);
  if (nd <= 0) return;
  int ebase = b * CAP;
  int count = min(gcur[b], CAP);
  hist[t] = 0;
  __syncthreads();
  for (int i = t; i < count; i += 1024)
    atomicAdd(&hist[packed[ebase + i] & 511], 1);
  __syncthreads();
  scan[t] = hist[t];
  __syncthreads();
  for (int off = 1; off < 1024; off <<= 1){
    int v = 0;
    if (t >= off) v = scan[t - off];
    __syncthreads();
    scan[t] += v;
    __syncthreads();
  }
  int excl = scan[t] - hist[t];      // exclusive prefix
  if (t < nd){
    int deg = hist[t];
    int o0 = ebase + excl;
    offA[d0 + t] = o0;
    offB[d0 + t] = o0 + deg;
    dinv[d0 + t] = deg > 0 ? rsqrtf((float)deg) : 0.f;
    cur[t] = excl;
  }
  __syncthreads();
  for (int i = t; i < count; i += 1024){
    int v = packed[ebase + i];
    int pos = atomicAdd(&cur[v & 511], 1);   // LDS atomic; scatter confined to ~56KB
    csr[ebase + pos] = v >> 9;
  }
}

// ---------------- x[N,32] @ W[4,32,16] -> z0(+bias_total), z1, z2, z3p(pre-scaled) ----------------
__global__ void k_xw4(const float* __restrict__ X, const float* __restrict__ W,
                      const float* __restrict__ b, const float* __restrict__ dinv,
                      float* __restrict__ z0, float* __restrict__ z1,
                      float* __restrict__ z2, float* __restrict__ z3p, int n){
  __shared__ float sW[2048];   // 4*32*16
  __shared__ float sb[16];
  for (int i = threadIdx.x; i < 2048; i += blockDim.x) sW[i] = W[i];
  if (threadIdx.x < 16)
    sb[threadIdx.x] = b[threadIdx.x] + b[16+threadIdx.x] + b[32+threadIdx.x] + b[48+threadIdx.x];
  __syncthreads();
  int v = blockIdx.x * blockDim.x + threadIdx.x;
  if (v >= n) return;
  float xr[32];
  const float4* xp = (const float4*)(X + (size_t)v * 32);
  #pragma unroll
  for (int j = 0; j < 8; j++){ float4 t = xp[j]; xr[4*j]=t.x; xr[4*j+1]=t.y; xr[4*j+2]=t.z; xr[4*j+3]=t.w; }
  float dv = dinv[v];
  #pragma unroll
  for (int k = 0; k < 4; k++){
    float o[16];
    #pragma unroll
    for (int c = 0; c < 16; c++) o[c] = 0.f;
    const float* wk = &sW[k * 512];
    #pragma unroll
    for (int i = 0; i < 32; i++){
      float xi = xr[i];
      #pragma unroll
      for (int c = 0; c < 16; c++) o[c] += xi * wk[i*16 + c];
    }
    float* dst;
    if (k == 0){
      #pragma unroll
      for (int c = 0; c < 16; c++) o[c] += sb[c];
      dst = z0;
    } else if (k == 1) dst = z1;
    else if (k == 2) dst = z2;
    else {
      #pragma unroll
      for (int c = 0; c < 16; c++) o[c] *= dv;
      dst = z3p;
    }
    float4* dp = (float4*)(dst + (size_t)v * 16);
    #pragma unroll
    for (int j = 0; j < 4; j++) dp[j] = make_float4(o[4*j], o[4*j+1], o[4*j+2], o[4*j+3]);
  }
}

// ---------------- propagation: s = dinv[v]*sum_e p[src] (+add[v]) (relu?) ; h=s, p=dinv*s ----------------
// 64 lanes per node: lane = esub*16 + c ; esub = 4 edges in flight, c = channel
__global__ void k_prop2(const int* __restrict__ offA, const int* __restrict__ offB,
                        const int* __restrict__ csr,
                        const float* __restrict__ dinv, const float* __restrict__ pin,
                        const float* __restrict__ addv, float* __restrict__ hout,
                        float* __restrict__ pout, int do_relu, int n){
  int v = (int)((blockIdx.x * (size_t)blockDim.x + threadIdx.x) >> 6);
  if (v >= n) return;
  int lane = threadIdx.x & 63;
  int c = lane & 15;
  int esub = lane >> 4;
  int e0 = offA[v], e1 = offB[v];
  float acc = 0.f;
  for (int e = e0 + esub; e < e1; e += 4){
    int src = csr[e];
    acc += pin[(size_t)src * 16 + c];
  }
  acc += __shfl_down(acc, 32);
  acc += __shfl_down(acc, 16);
  if (esub == 0){
    float dv = dinv[v];
    float s = dv * acc;
    if (addv) s += addv[(size_t)v * 16 + c];
    if (do_relu) s = fmaxf(s, 0.f);
    if (hout) hout[(size_t)v * 16 + c] = s;
    if (pout) pout[(size_t)v * 16 + c] = dv * s;
  }
}

// ---------------- layer2 combine: h2 = relu(sum_k g_k @ W2[k] + btot) ----------------
__global__ void k_lin4(const float* __restrict__ g0, const float* __restrict__ g1,
                       const float* __restrict__ g2, const float* __restrict__ g3,
                       const float* __restrict__ W, const float* __restrict__ b,
                       float* __restrict__ h2, int n){
  __shared__ float sW[2048];   // 4*16*32
  __shared__ float sb[32];
  for (int i = threadIdx.x; i < 2048; i += blockDim.x) sW[i] = W[i];
  if (threadIdx.x < 32)
    sb[threadIdx.x] = b[threadIdx.x] + b[32+threadIdx.x] + b[64+threadIdx.x] + b[96+threadIdx.x];
  __syncthreads();
  int v = blockIdx.x * blockDim.x + threadIdx.x;
  if (v >= n) return;
  float o[32];
  #pragma unroll
  for (int c = 0; c < 32; c++) o[c] = sb[c];
  #pragma unroll
  for (int k = 0; k < 4; k++){
    const float* gk = (k==0) ? g0 : (k==1) ? g1 : (k==2) ? g2 : g3;
    const float4* gp = (const float4*)(gk + (size_t)v * 16);
    float gr[16];
    #pragma unroll
    for (int j = 0; j < 4; j++){ float4 t = gp[j]; gr[4*j]=t.x; gr[4*j+1]=t.y; gr[4*j+2]=t.z; gr[4*j+3]=t.w; }
    const float* wk = &sW[k * 512];
    #pragma unroll
    for (int i = 0; i < 16; i++){
      float gi = gr[i];
      #pragma unroll
      for (int c = 0; c < 32; c++) o[c] += gi * wk[i*32 + c];
    }
  }
  float4* dp = (float4*)(h2 + (size_t)v * 32);
  #pragma unroll
  for (int j = 0; j < 8; j++)
    dp[j] = make_float4(fmaxf(o[4*j],0.f), fmaxf(o[4*j+1],0.f), fmaxf(o[4*j+2],0.f), fmaxf(o[4*j+3],0.f));
}

// ---------------- global mean pool (64 graphs, C=16) ----------------
__global__ void k_pool(const float* __restrict__ h, const int* __restrict__ batch,
                       float* __restrict__ pooled, float* __restrict__ cnt, int n){
  __shared__ float sacc[NGRAPH * 16];
  __shared__ float scnt[NGRAPH];
  for (int i = threadIdx.x; i < NGRAPH*16; i += blockDim.x) sacc[i] = 0.f;
  if (threadIdx.x < NGRAPH) scnt[threadIdx.x] = 0.f;
  __syncthreads();
  int t = blockIdx.x * blockDim.x + threadIdx.x;
  int c = t & 15;
  int stride = (gridDim.x * blockDim.x) >> 4;
  for (int v = t >> 4; v < n; v += stride){
    int b = batch[v];
    atomicAdd(&sacc[b*16 + c], h[(size_t)v*16 + c]);
    if (c == 0) atomicAdd(&scnt[b], 1.f);
  }
  __syncthreads();
  for (int i = threadIdx.x; i < NGRAPH*16; i += blockDim.x)
    if (sacc[i] != 0.f) atomicAdd(&pooled[i], sacc[i]);
  if (threadIdx.x < NGRAPH && scnt[threadIdx.x] != 0.f) atomicAdd(&cnt[threadIdx.x], scnt[threadIdx.x]);
}

// ---------------- head: pooled/cnt @ Wfc + bfc, log_softmax ----------------
__global__ void k_head(const float* __restrict__ pooled, const float* __restrict__ cnt,
                       const float* __restrict__ Wfc, const float* __restrict__ bfc,
                       float* __restrict__ out){
  int g = threadIdx.x;
  if (g >= NGRAPH) return;
  float cc = fmaxf(cnt[g], 1.f);
  float p[16];
  #pragma unroll
  for (int i = 0; i < 16; i++) p[i] = pooled[g*16 + i] / cc;
  float logits[NCLS];
  #pragma unroll
  for (int j = 0; j < NCLS; j++){
    float s = bfc[j];
    #pragma unroll
    for (int i = 0; i < 16; i++) s += p[i] * Wfc[i*NCLS + j];
    logits[j] = s;
  }
  float m = logits[0];
  #pragma unroll
  for (int j = 1; j < NCLS; j++) m = fmaxf(m, logits[j]);
  float l = 0.f;
  #pragma unroll
  for (int j = 0; j < NCLS; j++) l += expf(logits[j] - m);
  l = logf(l);
  #pragma unroll
  for (int j = 0; j < NCLS; j++) out[g*NCLS + j] = logits[j] - m - l;
}

// ---------------- launcher ----------------
extern "C" void kernel_launch(void* const* d_in, const int* in_sizes, int n_in,
                              void* d_out, int out_size, void* d_ws, size_t ws_size,
                              hipStream_t stream) {
  const float* x    = (const float*)d_in[0];
  const int*   ei   = (const int*)  d_in[1];
  const int*   batch= (const int*)  d_in[2];
  const float* W1   = (const float*)d_in[3];
  const float* b1   = (const float*)d_in[4];
  const float* W2   = (const float*)d_in[5];
  const float* b2   = (const float*)d_in[6];
  const float* W3   = (const float*)d_in[7];
  const float* b3   = (const float*)d_in[8];
  const float* Wfc  = (const float*)d_in[9];
  const float* bfc  = (const float*)d_in[10];
  float* out = (float*)d_out;

  const int N = in_sizes[0] / F_INPUT;
  const int E = in_sizes[1] / 2;
  const int* row = ei;
  const int* col = ei + E;
  const int nbuck = cdiv(N, DPB);   // 512 for N=200000

  // bump allocator over d_ws
  char* w = (char*)d_ws;
  auto alloc = [&](size_t bytes)->char*{
    char* p = w;
    w += (bytes + 255) & ~(size_t)255;
    return p;
  };
  int*   gcur    = (int*)  alloc((size_t)nbuck * 4);
  int*   csr     = (int*)  alloc((size_t)nbuck * CAP * 4);
  int*   offA    = (int*)  alloc((size_t)N * 4);
  int*   offB    = (int*)  alloc((size_t)N * 4);
  float* dinv    = (float*)alloc((size_t)N * 4);
  float* B0      = (float*)alloc((size_t)N * 16 * 4);
  float* B1      = (float*)alloc((size_t)N * 16 * 4);
  float* B2      = (float*)alloc((size_t)N * 16 * 4);
  float* B3      = (float*)alloc((size_t)N * 16 * 4);
  float* B4      = (float*)alloc((size_t)N * 16 * 4);
  float* B5      = (float*)alloc((size_t)N * 16 * 4);
  float* H2      = (float*)alloc((size_t)N * 32 * 4);
  float* pooled  = (float*)alloc((size_t)(NGRAPH*16 + NGRAPH) * 4);
  float* cnt     = pooled + NGRAPH*16;
  // packed aliases B0.. (dead during CSR build; first written by k_xw4 AFTER k_bfill)
  int*   packed  = (int*)B0;
  (void)ws_size; (void)n_in; (void)out_size;

  // ---- CSR build (bucketed two-phase) ----
  hipMemsetAsync(gcur, 0, (size_t)nbuck * 4, stream);
  k_part <<<cdiv(E, PART_CHUNK), 1024, 0, stream>>>(row, col, gcur, packed, E, nbuck);
  k_bfill<<<nbuck, 1024, 0, stream>>>(gcur, packed, csr, offA, offB, dinv, N);

  const int PROP_BLOCKS = cdiv(N, 4);  // 4 nodes(waves)/block

  // ---- Layer 1 (32 -> 16, Horner, propagate at C=16) ----
  k_xw4<<<cdiv(N,256), 256, 0, stream>>>(x, W1, b1, dinv, B0, B1, B2, B3, N);
  k_prop2<<<PROP_BLOCKS, 256, 0, stream>>>(offA, offB, csr, dinv, B3, B2, nullptr, B2, 0, N); // p2
  k_prop2<<<PROP_BLOCKS, 256, 0, stream>>>(offA, offB, csr, dinv, B2, B1, nullptr, B1, 0, N); // p1
  k_prop2<<<PROP_BLOCKS, 256, 0, stream>>>(offA, offB, csr, dinv, B1, B0, B0, B3, 1, N);      // h1=B0, p_h1=B3

  // ---- Layer 2 (16 -> 32, standard form, propagate at C=16) ----
  k_prop2<<<PROP_BLOCKS, 256, 0, stream>>>(offA, offB, csr, dinv, B3, nullptr, B1, B2, 0, N); // g1=B1, p_g1=B2
  k_prop2<<<PROP_BLOCKS, 256, 0, stream>>>(offA, offB, csr, dinv, B2, nullptr, B4, B5, 0, N); // g2=B4, p_g2=B5
  k_prop2<<<PROP_BLOCKS, 256, 0, stream>>>(offA, offB, csr, dinv, B5, nullptr, B2, nullptr, 0, N); // g3=B2
  k_lin4<<<cdiv(N,256), 256, 0, stream>>>(B0, B1, B4, B2, W2, b2, H2, N);

  // ---- Layer 3 (32 -> 16, Horner) ----
  k_xw4<<<cdiv(N,256), 256, 0, stream>>>(H2, W3, b3, dinv, B0, B1, B2, B3, N);
  k_prop2<<<PROP_BLOCKS, 256, 0, stream>>>(offA, offB, csr, dinv, B3, B2, nullptr, B2, 0, N);
  k_prop2<<<PROP_BLOCKS, 256, 0, stream>>>(offA, offB, csr, dinv, B2, B1, nullptr, B1, 0, N);
  k_prop2<<<PROP_BLOCKS, 256, 0, stream>>>(offA, offB, csr, dinv, B1, B0, B4, nullptr, 1, N); // h3=B4

  // ---- pool + head ----
  hipMemsetAsync(pooled, 0, (size_t)(NGRAPH*16 + NGRAPH) * 4, stream);
  k_pool<<<512, 256, 0, stream>>>(B4, batch, pooled, cnt, N);
  k_head<<<1, 64, 0, stream>>>(pooled, cnt, Wfc, bfc, out);
}

// Round 3
// 1007.214 us; speedup vs baseline: 2.5089x; 1.7868x over previous
//
#include <hip/hip_runtime.h>
#include <hip/hip_fp16.h>

// ---------------- problem constants ----------------
#define F_INPUT 32
#define NGRAPH 64
#define NCLS 13

// CSR bucket-build parameters
#define DPB 391          // dsts per bucket (local_dst fits 9 bits)
#define NBUCK_MAX 512
#define CAP 14336        // per-bucket edge capacity (mean 12500, +16 sigma)
#define PART_CHUNK 8192  // edges per partition block

static inline int cdiv(int a, int b){ return (a + b - 1) / b; }

// ---------------- fp16 pack/unpack helpers ----------------
__device__ inline uint2 pack4h(float s0, float s1, float s2, float s3){
  __half2 a = __floats2half2_rn(s0, s1);
  __half2 b = __floats2half2_rn(s2, s3);
  uint2 r;
  r.x = *(unsigned int*)&a;
  r.y = *(unsigned int*)&b;
  return r;
}
__device__ inline void unpack4h(uint2 q, float& f0, float& f1, float& f2, float& f3){
  __half2 a = *(__half2*)&q.x;
  __half2 b = *(__half2*)&q.y;
  float2 fa = __half22float2(a), fb = __half22float2(b);
  f0 = fa.x; f1 = fa.y; f2 = fb.x; f3 = fb.y;
}

// ---------------- phase A: partition edges into dst-range buckets ----------------
// packed[b*CAP + j] = (src << 9) | (dst - b*DPB)
__global__ __launch_bounds__(1024)
void k_part(const int* __restrict__ row, const int* __restrict__ col,
            int* __restrict__ gcur, int* __restrict__ packed, int E, int nbuck){
  __shared__ int scol[PART_CHUNK];
  __shared__ int hist[NBUCK_MAX];
  __shared__ int gbase[NBUCK_MAX];
  __shared__ int cur[NBUCK_MAX];
  int t = threadIdx.x;
  for (int i = t; i < NBUCK_MAX; i += 1024) hist[i] = 0;
  __syncthreads();
  int base = blockIdx.x * PART_CHUNK;
  int nloc = min(PART_CHUNK, E - base);
  for (int i = t; i < nloc; i += 1024){
    int c = col[base + i];
    scol[i] = c;
    atomicAdd(&hist[c / DPB], 1);
  }
  __syncthreads();
  if (t < nbuck){
    gbase[t] = atomicAdd(&gcur[t], hist[t]);   // one global atomic per bucket per block
    cur[t] = 0;
  }
  __syncthreads();
  for (int i = t; i < nloc; i += 1024){
    int c = scol[i];
    int b = c / DPB;
    int j = gbase[b] + atomicAdd(&cur[b], 1);
    if (j < CAP){
      int src = row[base + i];
      packed[(size_t)b * CAP + j] = (src << 9) | (c - b * DPB);
    }
  }
}

// ---------------- phase B: per-bucket CSR fill + offsets + dinv ----------------
__global__ __launch_bounds__(1024)
void k_bfill(const int* __restrict__ gcur, const int* __restrict__ packed,
             int* __restrict__ csr, int* __restrict__ offA, int* __restrict__ offB,
             float* __restrict__ dinv, int N){
  __shared__ int hist[1024];
  __shared__ int scan[1024];
  __shared__ int cur[512];
  int b = blockIdx.x;
  int t = threadIdx.x;
  int d0 = b * DPB;
  int nd = min(DPB, N - d0);
  if (nd <= 0) return;
  int ebase = b * CAP;
  int count = min(gcur[b], CAP);
  hist[t] = 0;
  __syncthreads();
  for (int i = t; i < count; i += 1024)
    atomicAdd(&hist[packed[ebase + i] & 511], 1);
  __syncthreads();
  scan[t] = hist[t];
  __syncthreads();
  for (int off = 1; off < 1024; off <<= 1){
    int v = 0;
    if (t >= off) v = scan[t - off];
    __syncthreads();
    scan[t] += v;
    __syncthreads();
  }
  int excl = scan[t] - hist[t];      // exclusive prefix
  if (t < nd){
    int deg = hist[t];
    int o0 = ebase + excl;
    offA[d0 + t] = o0;
    offB[d0 + t] = o0 + deg;
    dinv[d0 + t] = deg > 0 ? rsqrtf((float)deg) : 0.f;
    cur[t] = excl;
  }
  __syncthreads();
  for (int i = t; i < count; i += 1024){
    int v = packed[ebase + i];
    int pos = atomicAdd(&cur[v & 511], 1);   // LDS atomic; scatter confined to ~56KB
    csr[ebase + pos] = v >> 9;
  }
}

// ---------------- x[N,32] @ W[4,32,16] -> z0(+bias_total), z1, z2, z3p(pre-scaled), fp16 out ----------------
__global__ void k_xw4h(const float* __restrict__ X, const float* __restrict__ W,
                       const float* __restrict__ b, const float* __restrict__ dinv,
                       uint2* __restrict__ z0, uint2* __restrict__ z1,
                       uint2* __restrict__ z2, uint2* __restrict__ z3p, int n){
  __shared__ float sW[2048];   // 4*32*16
  __shared__ float sb[16];
  for (int i = threadIdx.x; i < 2048; i += blockDim.x) sW[i] = W[i];
  if (threadIdx.x < 16)
    sb[threadIdx.x] = b[threadIdx.x] + b[16+threadIdx.x] + b[32+threadIdx.x] + b[48+threadIdx.x];
  __syncthreads();
  int v = blockIdx.x * blockDim.x + threadIdx.x;
  if (v >= n) return;
  float xr[32];
  const float4* xp = (const float4*)(X + (size_t)v * 32);
  #pragma unroll
  for (int j = 0; j < 8; j++){ float4 t = xp[j]; xr[4*j]=t.x; xr[4*j+1]=t.y; xr[4*j+2]=t.z; xr[4*j+3]=t.w; }
  float dv = dinv[v];
  #pragma unroll
  for (int k = 0; k < 4; k++){
    float o[16];
    #pragma unroll
    for (int c = 0; c < 16; c++) o[c] = 0.f;
    const float* wk = &sW[k * 512];
    #pragma unroll
    for (int i = 0; i < 32; i++){
      float xi = xr[i];
      #pragma unroll
      for (int c = 0; c < 16; c++) o[c] += xi * wk[i*16 + c];
    }
    uint2* dst;
    if (k == 0){
      #pragma unroll
      for (int c = 0; c < 16; c++) o[c] += sb[c];
      dst = z0;
    } else if (k == 1) dst = z1;
    else if (k == 2) dst = z2;
    else {
      #pragma unroll
      for (int c = 0; c < 16; c++) o[c] *= dv;
      dst = z3p;
    }
    uint2* dp = dst + (size_t)v * 4;
    #pragma unroll
    for (int j = 0; j < 4; j++) dp[j] = pack4h(o[4*j], o[4*j+1], o[4*j+2], o[4*j+3]);
  }
}

// ---------------- propagation (fp16 features, f32 accumulate) ----------------
// 64 lanes per node: lane = esub*4 + cq ; esub = 16 edges in flight, cq = channel-quad (8B/lane)
__global__ void k_prop3(const int* __restrict__ offA, const int* __restrict__ offB,
                        const int* __restrict__ csr,
                        const float* __restrict__ dinv, const uint2* __restrict__ pin,
                        const uint2* __restrict__ addv, uint2* __restrict__ hout,
                        uint2* __restrict__ pout, int do_relu, int n){
  int v = (int)((blockIdx.x * (size_t)blockDim.x + threadIdx.x) >> 6);
  if (v >= n) return;
  int lane = threadIdx.x & 63;
  int cq = lane & 3;
  int esub = lane >> 2;
  int e0 = offA[v], e1 = offB[v];
  float a0 = 0.f, a1 = 0.f, a2 = 0.f, a3 = 0.f;
  for (int e = e0 + esub; e < e1; e += 16){
    int src = csr[e];
    uint2 q = pin[(size_t)src * 4 + cq];
    float f0, f1, f2, f3;
    unpack4h(q, f0, f1, f2, f3);
    a0 += f0; a1 += f1; a2 += f2; a3 += f3;
  }
  // reduce across esub groups (lane strides 32,16,8,4)
  a0 += __shfl_down(a0, 32); a1 += __shfl_down(a1, 32); a2 += __shfl_down(a2, 32); a3 += __shfl_down(a3, 32);
  a0 += __shfl_down(a0, 16); a1 += __shfl_down(a1, 16); a2 += __shfl_down(a2, 16); a3 += __shfl_down(a3, 16);
  a0 += __shfl_down(a0,  8); a1 += __shfl_down(a1,  8); a2 += __shfl_down(a2,  8); a3 += __shfl_down(a3,  8);
  a0 += __shfl_down(a0,  4); a1 += __shfl_down(a1,  4); a2 += __shfl_down(a2,  4); a3 += __shfl_down(a3,  4);
  if (esub == 0){
    float dv = dinv[v];
    float s0 = dv * a0, s1 = dv * a1, s2 = dv * a2, s3 = dv * a3;
    if (addv){
      float g0, g1, g2, g3;
      unpack4h(addv[(size_t)v * 4 + cq], g0, g1, g2, g3);
      s0 += g0; s1 += g1; s2 += g2; s3 += g3;
    }
    if (do_relu){
      s0 = fmaxf(s0, 0.f); s1 = fmaxf(s1, 0.f); s2 = fmaxf(s2, 0.f); s3 = fmaxf(s3, 0.f);
    }
    if (hout) hout[(size_t)v * 4 + cq] = pack4h(s0, s1, s2, s3);
    if (pout) pout[(size_t)v * 4 + cq] = pack4h(dv * s0, dv * s1, dv * s2, dv * s3);
  }
}

// ---------------- layer2 combine: h2 = relu(sum_k g_k @ W2[k] + btot), fp16 in, f32 out ----------------
__global__ void k_lin4h(const uint2* __restrict__ g0, const uint2* __restrict__ g1,
                        const uint2* __restrict__ g2, const uint2* __restrict__ g3,
                        const float* __restrict__ W, const float* __restrict__ b,
                        float* __restrict__ h2, int n){
  __shared__ float sW[2048];   // 4*16*32
  __shared__ float sb[32];
  for (int i = threadIdx.x; i < 2048; i += blockDim.x) sW[i] = W[i];
  if (threadIdx.x < 32)
    sb[threadIdx.x] = b[threadIdx.x] + b[32+threadIdx.x] + b[64+threadIdx.x] + b[96+threadIdx.x];
  __syncthreads();
  int v = blockIdx.x * blockDim.x + threadIdx.x;
  if (v >= n) return;
  float o[32];
  #pragma unroll
  for (int c = 0; c < 32; c++) o[c] = sb[c];
  #pragma unroll
  for (int k = 0; k < 4; k++){
    const uint2* gk = (k==0) ? g0 : (k==1) ? g1 : (k==2) ? g2 : g3;
    const uint2* gp = gk + (size_t)v * 4;
    float gr[16];
    #pragma unroll
    for (int j = 0; j < 4; j++) unpack4h(gp[j], gr[4*j], gr[4*j+1], gr[4*j+2], gr[4*j+3]);
    const float* wk = &sW[k * 512];
    #pragma unroll
    for (int i = 0; i < 16; i++){
      float gi = gr[i];
      #pragma unroll
      for (int c = 0; c < 32; c++) o[c] += gi * wk[i*32 + c];
    }
  }
  float4* dp = (float4*)(h2 + (size_t)v * 32);
  #pragma unroll
  for (int j = 0; j < 8; j++)
    dp[j] = make_float4(fmaxf(o[4*j],0.f), fmaxf(o[4*j+1],0.f), fmaxf(o[4*j+2],0.f), fmaxf(o[4*j+3],0.f));
}

// ---------------- global mean pool (64 graphs, C=16, fp16 in) ----------------
__global__ void k_poolh(const __half* __restrict__ h, const int* __restrict__ batch,
                        float* __restrict__ pooled, float* __restrict__ cnt, int n){
  __shared__ float sacc[NGRAPH * 16];
  __shared__ float scnt[NGRAPH];
  for (int i = threadIdx.x; i < NGRAPH*16; i += blockDim.x) sacc[i] = 0.f;
  if (threadIdx.x < NGRAPH) scnt[threadIdx.x] = 0.f;
  __syncthreads();
  int t = blockIdx.x * blockDim.x + threadIdx.x;
  int c = t & 15;
  int stride = (gridDim.x * blockDim.x) >> 4;
  for (int v = t >> 4; v < n; v += stride){
    int b = batch[v];
    atomicAdd(&sacc[b*16 + c], __half2float(h[(size_t)v*16 + c]));
    if (c == 0) atomicAdd(&scnt[b], 1.f);
  }
  __syncthreads();
  for (int i = threadIdx.x; i < NGRAPH*16; i += blockDim.x)
    if (sacc[i] != 0.f) atomicAdd(&pooled[i], sacc[i]);
  if (threadIdx.x < NGRAPH && scnt[threadIdx.x] != 0.f) atomicAdd(&cnt[threadIdx.x], scnt[threadIdx.x]);
}

// ---------------- head: pooled/cnt @ Wfc + bfc, log_softmax ----------------
__global__ void k_head(const float* __restrict__ pooled, const float* __restrict__ cnt,
                       const float* __restrict__ Wfc, const float* __restrict__ bfc,
                       float* __restrict__ out){
  int g = threadIdx.x;
  if (g >= NGRAPH) return;
  float cc = fmaxf(cnt[g], 1.f);
  float p[16];
  #pragma unroll
  for (int i = 0; i < 16; i++) p[i] = pooled[g*16 + i] / cc;
  float logits[NCLS];
  #pragma unroll
  for (int j = 0; j < NCLS; j++){
    float s = bfc[j];
    #pragma unroll
    for (int i = 0; i < 16; i++) s += p[i] * Wfc[i*NCLS + j];
    logits[j] = s;
  }
  float m = logits[0];
  #pragma unroll
  for (int j = 1; j < NCLS; j++) m = fmaxf(m, logits[j]);
  float l = 0.f;
  #pragma unroll
  for (int j = 0; j < NCLS; j++) l += expf(logits[j] - m);
  l = logf(l);
  #pragma unroll
  for (int j = 0; j < NCLS; j++) out[g*NCLS + j] = logits[j] - m - l;
}

// ---------------- launcher ----------------
extern "C" void kernel_launch(void* const* d_in, const int* in_sizes, int n_in,
                              void* d_out, int out_size, void* d_ws, size_t ws_size,
                              hipStream_t stream) {
  const float* x    = (const float*)d_in[0];
  const int*   ei   = (const int*)  d_in[1];
  const int*   batch= (const int*)  d_in[2];
  const float* W1   = (const float*)d_in[3];
  const float* b1   = (const float*)d_in[4];
  const float* W2   = (const float*)d_in[5];
  const float* b2   = (const float*)d_in[6];
  const float* W3   = (const float*)d_in[7];
  const float* b3   = (const float*)d_in[8];
  const float* Wfc  = (const float*)d_in[9];
  const float* bfc  = (const float*)d_in[10];
  float* out = (float*)d_out;

  const int N = in_sizes[0] / F_INPUT;
  const int E = in_sizes[1] / 2;
  const int* row = ei;
  const int* col = ei + E;
  const int nbuck = cdiv(N, DPB);   // 512 for N=200000

  // bump allocator over d_ws
  char* w = (char*)d_ws;
  auto alloc = [&](size_t bytes)->char*{
    char* p = w;
    w += (bytes + 255) & ~(size_t)255;
    return p;
  };
  int*   gcur    = (int*)  alloc((size_t)nbuck * 4);
  int*   csr     = (int*)  alloc((size_t)nbuck * CAP * 4);
  int*   offA    = (int*)  alloc((size_t)N * 4);
  int*   offB    = (int*)  alloc((size_t)N * 4);
  float* dinv    = (float*)alloc((size_t)N * 4);
  // B buffers hold fp16 features (N x 16 x 2B) but keep f32-size allocation
  // so `packed` (29.3MB) can alias B0..B2 during CSR build.
  uint2* B0      = (uint2*)alloc((size_t)N * 16 * 4);
  uint2* B1      = (uint2*)alloc((size_t)N * 16 * 4);
  uint2* B2      = (uint2*)alloc((size_t)N * 16 * 4);
  uint2* B3      = (uint2*)alloc((size_t)N * 16 * 4);
  uint2* B4      = (uint2*)alloc((size_t)N * 16 * 4);
  uint2* B5      = (uint2*)alloc((size_t)N * 16 * 4);
  float* H2      = (float*)alloc((size_t)N * 32 * 4);
  float* pooled  = (float*)alloc((size_t)(NGRAPH*16 + NGRAPH) * 4);
  float* cnt     = pooled + NGRAPH*16;
  // packed aliases B0..B2 (dead during CSR build; B's first written after k_bfill)
  int*   packed  = (int*)B0;
  (void)ws_size; (void)n_in; (void)out_size;

  // ---- CSR build (bucketed two-phase) ----
  hipMemsetAsync(gcur, 0, (size_t)nbuck * 4, stream);
  k_part <<<cdiv(E, PART_CHUNK), 1024, 0, stream>>>(row, col, gcur, packed, E, nbuck);
  k_bfill<<<nbuck, 1024, 0, stream>>>(gcur, packed, csr, offA, offB, dinv, N);

  const int PROP_BLOCKS = cdiv(N, 4);  // 4 waves(nodes)/block

  // ---- Layer 1 (32 -> 16, Horner, propagate at C=16) ----
  k_xw4h<<<cdiv(N,256), 256, 0, stream>>>(x, W1, b1, dinv, B0, B1, B2, B3, N);
  k_prop3<<<PROP_BLOCKS, 256, 0, stream>>>(offA, offB, csr, dinv, B3, B2, nullptr, B2, 0, N); // p2
  k_prop3<<<PROP_BLOCKS, 256, 0, stream>>>(offA, offB, csr, dinv, B2, B1, nullptr, B1, 0, N); // p1
  k_prop3<<<PROP_BLOCKS, 256, 0, stream>>>(offA, offB, csr, dinv, B1, B0, B0, B3, 1, N);      // h1=B0, p_h1=B3

  // ---- Layer 2 (16 -> 32, standard form, propagate at C=16) ----
  k_prop3<<<PROP_BLOCKS, 256, 0, stream>>>(offA, offB, csr, dinv, B3, nullptr, B1, B2, 0, N); // g1=B1, p_g1=B2
  k_prop3<<<PROP_BLOCKS, 256, 0, stream>>>(offA, offB, csr, dinv, B2, nullptr, B4, B5, 0, N); // g2=B4, p_g2=B5
  k_prop3<<<PROP_BLOCKS, 256, 0, stream>>>(offA, offB, csr, dinv, B5, nullptr, B2, nullptr, 0, N); // g3=B2
  k_lin4h<<<cdiv(N,256), 256, 0, stream>>>(B0, B1, B4, B2, W2, b2, H2, N);

  // ---- Layer 3 (32 -> 16, Horner) ----
  k_xw4h<<<cdiv(N,256), 256, 0, stream>>>(H2, W3, b3, dinv, B0, B1, B2, B3, N);
  k_prop3<<<PROP_BLOCKS, 256, 0, stream>>>(offA, offB, csr, dinv, B3, B2, nullptr, B2, 0, N);
  k_prop3<<<PROP_BLOCKS, 256, 0, stream>>>(offA, offB, csr, dinv, B2, B1, nullptr, B1, 0, N);
  k_prop3<<<PROP_BLOCKS, 256, 0, stream>>>(offA, offB, csr, dinv, B1, B0, B4, nullptr, 1, N); // h3=B4

  // ---- pool + head ----
  hipMemsetAsync(pooled, 0, (size_t)(NGRAPH*16 + NGRAPH) * 4, stream);
  k_poolh<<<512, 256, 0, stream>>>((const __half*)B4, batch, pooled, cnt, N);
  k_head<<<1, 64, 0, stream>>>(pooled, cnt, Wfc, bfc, out);
}